// Round 5
// baseline (205.505 us; speedup 1.0000x reference)
//
#include <hip/hip_runtime.h>

#define EPS 1e-5f

constexpr int FIN = 22;   // input feature dim
constexpr int XP  = 32;   // padded x feature stride
constexpr int H   = 128;  // hidden dim

// bf16 helpers (bit-level, RN-even)
static __device__ __forceinline__ unsigned short f2bf(float f) {
    unsigned int u = __float_as_uint(f);
    unsigned int r = (u + 0x7fffu + ((u >> 16) & 1u)) >> 16;
    return (unsigned short)r;
}
static __device__ __forceinline__ float bflo(unsigned int u) {  // low bf16 of a dword
    return __uint_as_float(u << 16);
}
static __device__ __forceinline__ float bfhi(unsigned int u) {  // high bf16 of a dword
    return __uint_as_float(u & 0xffff0000u);
}

// ---------------- degree histogram ----------------
__global__ void deg_kernel(const int* __restrict__ ei, int* __restrict__ degi, int E) {
    int e = blockIdx.x * blockDim.x + threadIdx.x;
    if (e < E) atomicAdd(&degi[ei[E + e]], 1);
}

// ---------------- BN constant prep ----------------
__global__ void prep_kernel(const float* __restrict__ b1, const float* __restrict__ mean1,
                            const float* __restrict__ var1, const float* __restrict__ gamma1,
                            const float* __restrict__ beta1,
                            const float* __restrict__ b2, const float* __restrict__ mean2,
                            const float* __restrict__ var2, const float* __restrict__ gamma2,
                            const float* __restrict__ beta2,
                            float* __restrict__ A1f, float* __restrict__ B1f,
                            float* __restrict__ A2f, float* __restrict__ B2f) {
    int t = threadIdx.x;
    if (t < H) {
        float A1 = gamma1[t] * rsqrtf(var1[t] + EPS);
        A1f[t] = A1;
        B1f[t] = (b1[t] - mean1[t]) * A1 + beta1[t];
        float A2 = gamma2[t] * rsqrtf(var2[t] + EPS);
        A2f[t] = A2;
        B2f[t] = (b2[t] - mean2[t]) * A2 + beta2[t];
    }
}

// ---------------- scan phase A: per-block exclusive scan + dinv + xr = bf16(x*dinv) ----------------
__global__ __launch_bounds__(256) void scanA_kernel(
    const int* __restrict__ degi, const float* __restrict__ x,
    int* __restrict__ offs, int* __restrict__ bsum,
    float* __restrict__ dinv, unsigned short* __restrict__ xb, int N) {
    __shared__ int sh[256];
    const int t = threadIdx.x;
    const int i = blockIdx.x * 256 + t;
    int v = (i < N) ? degi[i] : 0;
    sh[t] = v;
    __syncthreads();
    int val = v;
    for (int off = 1; off < 256; off <<= 1) {
        int add = (t >= off) ? sh[t - off] : 0;
        __syncthreads();
        val += add;
        sh[t] = val;
        __syncthreads();
    }
    if (i < N) offs[i] = val - v;          // exclusive within block
    if (t == 255) bsum[blockIdx.x] = val;  // block total
    if (i < N) {
        float di = rsqrtf((float)v + 1.0f); // +1 self-loop
        dinv[i] = di;
#pragma unroll
        for (int k = 0; k < XP; ++k)
            xb[i * XP + k] = (k < FIN) ? f2bf(x[i * FIN + k] * di) : (unsigned short)0;
    }
}

// ---------------- scan phase B: exclusive scan of block sums ----------------
__global__ __launch_bounds__(256) void scanB_kernel(int* __restrict__ bsum, int nb) {
    __shared__ int sh[256];
    const int t = threadIdx.x;
    int v = (t < nb) ? bsum[t] : 0;
    sh[t] = v;
    __syncthreads();
    int val = v;
    for (int off = 1; off < 256; off <<= 1) {
        int add = (t >= off) ? sh[t - off] : 0;
        __syncthreads();
        val += add;
        sh[t] = val;
        __syncthreads();
    }
    if (t < nb) bsum[t] = val - v;
}

// ---------------- scan phase C: add block base ----------------
__global__ void scanC_kernel(int* __restrict__ offs, const int* __restrict__ bsum, int N) {
    int i = blockIdx.x * blockDim.x + threadIdx.x;
    if (i < N) offs[i] += bsum[blockIdx.x];
}

// ---------------- CSR fill (source index only, 4B/edge) ----------------
__global__ void fill_kernel(const int* __restrict__ ei, int* __restrict__ offs,
                            int* __restrict__ csrS, int E) {
    int e = blockIdx.x * blockDim.x + threadIdx.x;
    if (e >= E) return;
    int s = ei[e], d = ei[E + e];
    int pos = atomicAdd(&offs[d], 1);
    csrS[pos] = s;
}
// after fill: range of node d = [ d ? offs[d-1] : 0,  offs[d] )

// ---------------- layer-1 gather: unweighted sum of pre-scaled xr rows, *dinv at end ----------------
__global__ __launch_bounds__(256) void gather_x_kernel(
    const unsigned short* __restrict__ xb, const float* __restrict__ dinv,
    const int* __restrict__ offs, const int* __restrict__ csrS,
    float* __restrict__ xa, int N) {
    const int tid  = threadIdx.x;
    const int node = blockIdx.x * 4 + (tid >> 6);
    const int lane = tid & 63;
    if (node >= N) return;
    const int g  = lane >> 3;      // group 0..7
    const int fl = lane & 7;       // lane in group
    const int beg = node ? offs[node - 1] : 0;
    const int end = offs[node];

    float acc0 = 0.f, acc1 = 0.f, acc2 = 0.f, acc3 = 0.f;
    if (g == 0) {  // self row, weight 1 (own dinv already folded in)
        ushort4 v = *reinterpret_cast<const ushort4*>(xb + (size_t)node * XP + fl * 4);
        acc0 = bflo(v.x); acc1 = bflo(v.y);
        acc2 = bflo(v.z); acc3 = bflo(v.w);
    }
    for (int e = beg + g; e < end; e += 8) {
        int s = csrS[e];
        ushort4 v = *reinterpret_cast<const ushort4*>(xb + (size_t)s * XP + fl * 4);
        acc0 += bflo(v.x); acc1 += bflo(v.y);
        acc2 += bflo(v.z); acc3 += bflo(v.w);
    }
#pragma unroll
    for (int off = 8; off < 64; off <<= 1) {
        acc0 += __shfl_xor(acc0, off);
        acc1 += __shfl_xor(acc1, off);
        acc2 += __shfl_xor(acc2, off);
        acc3 += __shfl_xor(acc3, off);
    }
    if (g == 0) {
        float di = dinv[node];
        float4 o = make_float4(acc0 * di, acc1 * di, acc2 * di, acc3 * di);
        *reinterpret_cast<float4*>(xa + (size_t)node * XP + fl * 4) = o;
    }
}

// ---------------- fused gemm1+BN1+ReLU+gemm2 (h1 stays in LDS); h2r = h2*A2*dinv ----------------
__global__ __launch_bounds__(256) void gemm12_kernel(
    const float* __restrict__ xa, const float* __restrict__ W1, const float* __restrict__ W2,
    const float* __restrict__ A1f, const float* __restrict__ B1f, const float* __restrict__ A2f,
    const float* __restrict__ dinv, unsigned short* __restrict__ h2b, int N) {
    __shared__ float lds1[16 * XP];        // xa tile
    __shared__ float lds2[H * 20];         // h1 tile, transposed [k][row], pad 20
    const int tid = threadIdx.x;
    const int m0  = blockIdx.x * 16;

    for (int idx = tid; idx < 16 * XP; idx += 256) {
        int row = m0 + (idx >> 5);
        lds1[idx] = (row < N) ? xa[(size_t)m0 * XP + idx] : 0.0f;
    }
    __syncthreads();

    const int f  = tid & 127;
    const int mg = tid >> 7;

    // gemm1
    float acc1[8];
#pragma unroll
    for (int j = 0; j < 8; ++j) acc1[j] = 0.0f;
    for (int k = 0; k < FIN; ++k) {
        float w = W1[k * H + f];
#pragma unroll
        for (int j = 0; j < 8; ++j) acc1[j] += lds1[(mg * 8 + j) * XP + k] * w;
    }
    const float A1 = A1f[f], B1 = B1f[f];
    float4 h1a, h1b;
    h1a.x = fmaxf(acc1[0] * A1 + B1, 0.f); h1a.y = fmaxf(acc1[1] * A1 + B1, 0.f);
    h1a.z = fmaxf(acc1[2] * A1 + B1, 0.f); h1a.w = fmaxf(acc1[3] * A1 + B1, 0.f);
    h1b.x = fmaxf(acc1[4] * A1 + B1, 0.f); h1b.y = fmaxf(acc1[5] * A1 + B1, 0.f);
    h1b.z = fmaxf(acc1[6] * A1 + B1, 0.f); h1b.w = fmaxf(acc1[7] * A1 + B1, 0.f);
    *reinterpret_cast<float4*>(&lds2[f * 20 + mg * 8])     = h1a;
    *reinterpret_cast<float4*>(&lds2[f * 20 + mg * 8 + 4]) = h1b;
    __syncthreads();

    // gemm2
    float acc2[8];
#pragma unroll
    for (int j = 0; j < 8; ++j) acc2[j] = 0.0f;
    for (int k = 0; k < H; ++k) {
        float w = W2[k * H + f];
        float4 ha = *reinterpret_cast<const float4*>(&lds2[k * 20 + mg * 8]);
        float4 hb = *reinterpret_cast<const float4*>(&lds2[k * 20 + mg * 8 + 4]);
        acc2[0] += ha.x * w; acc2[1] += ha.y * w; acc2[2] += ha.z * w; acc2[3] += ha.w * w;
        acc2[4] += hb.x * w; acc2[5] += hb.y * w; acc2[6] += hb.z * w; acc2[7] += hb.w * w;
    }
    const float A2 = A2f[f];
#pragma unroll
    for (int j = 0; j < 8; ++j) {
        int node = m0 + mg * 8 + j;
        if (node < N) {
            float sc = A2 * dinv[node];   // fold own dinv into stored row
            h2b[(size_t)node * H + f] = f2bf(acc2[j] * sc);
        }
    }
}

// ---------------- fused: layer-2 gather (pure row sum) + BN2 + ReLU + FC + sigmoid ----------------
__global__ __launch_bounds__(256) void gfinal_kernel(
    const unsigned short* __restrict__ h2b, const float* __restrict__ dinv,
    const int* __restrict__ offs, const int* __restrict__ csrS,
    const float* __restrict__ B2f, const float* __restrict__ Wfc,
    const float* __restrict__ bfc, float* __restrict__ out, int N) {
    const int tid  = threadIdx.x;
    const int node = blockIdx.x * 4 + (tid >> 6);
    const int lane = tid & 63;
    if (node >= N) return;
    const int g  = lane >> 4;      // group 0..3
    const int fl = lane & 15;      // lane in group
    const int f0 = fl * 8;
    const int beg = node ? offs[node - 1] : 0;
    const int end = offs[node];

    float acc[8];
#pragma unroll
    for (int j = 0; j < 8; ++j) acc[j] = 0.0f;

    if (g == 0) {  // self row, weight 1
        uint4 v = *reinterpret_cast<const uint4*>(h2b + (size_t)node * H + f0);
        acc[0] = bflo(v.x); acc[1] = bfhi(v.x);
        acc[2] = bflo(v.y); acc[3] = bfhi(v.y);
        acc[4] = bflo(v.z); acc[5] = bfhi(v.z);
        acc[6] = bflo(v.w); acc[7] = bfhi(v.w);
    }
    for (int e = beg + g; e < end; e += 4) {
        int s = csrS[e];
        uint4 v = *reinterpret_cast<const uint4*>(h2b + (size_t)s * H + f0);
        acc[0] += bflo(v.x); acc[1] += bfhi(v.x);
        acc[2] += bflo(v.y); acc[3] += bfhi(v.y);
        acc[4] += bflo(v.z); acc[5] += bfhi(v.z);
        acc[6] += bflo(v.w); acc[7] += bfhi(v.w);
    }
#pragma unroll
    for (int j = 0; j < 8; ++j) {
        acc[j] += __shfl_xor(acc[j], 16);
        acc[j] += __shfl_xor(acc[j], 32);
    }
    const float di = dinv[node];
    float p = 0.0f;
#pragma unroll
    for (int j = 0; j < 8; ++j)
        p += fmaxf(acc[j] * di + B2f[f0 + j], 0.0f) * Wfc[f0 + j];
#pragma unroll
    for (int off = 1; off < 16; off <<= 1) p += __shfl_xor(p, off);
    if (lane == 0) out[node] = 1.0f / (1.0f + expf(-(p + bfc[0])));
}

static inline size_t align4w(size_t w) { return (w + 3) & ~(size_t)3; }  // 16B align (words)

extern "C" void kernel_launch(void* const* d_in, const int* in_sizes, int n_in,
                              void* d_out, int out_size, void* d_ws, size_t ws_size,
                              hipStream_t stream) {
    const float* x      = (const float*)d_in[0];
    const int*   ei     = (const int*)d_in[1];
    const float* W1     = (const float*)d_in[2];
    const float* b1     = (const float*)d_in[3];
    const float* gamma1 = (const float*)d_in[4];
    const float* beta1  = (const float*)d_in[5];
    const float* mean1  = (const float*)d_in[6];
    const float* var1   = (const float*)d_in[7];
    const float* W2     = (const float*)d_in[8];
    const float* b2     = (const float*)d_in[9];
    const float* gamma2 = (const float*)d_in[10];
    const float* beta2  = (const float*)d_in[11];
    const float* mean2  = (const float*)d_in[12];
    const float* var2   = (const float*)d_in[13];
    const float* Wfc    = (const float*)d_in[14];
    const float* bfc    = (const float*)d_in[15];
    float* out = (float*)d_out;

    const int N = in_sizes[0] / FIN;   // 50000
    const int E = in_sizes[1] / 2;     // 800000
    const int NB = (N + 255) / 256;

    // workspace layout (4-byte words, 16B-aligned sections)
    int* base = (int*)d_ws;
    size_t o = 0;
    int*   degi = base + o;                o = align4w(o + N);
    float* dinv = (float*)(base + o);      o = align4w(o + N);
    int*   offs = base + o;                o = align4w(o + N);
    int*   bsum = base + o;                o = align4w(o + 256);
    float* A1f  = (float*)(base + o);      o = align4w(o + H);
    float* B1f  = (float*)(base + o);      o = align4w(o + H);
    float* A2f  = (float*)(base + o);      o = align4w(o + H);
    float* B2f  = (float*)(base + o);      o = align4w(o + H);
    int*   csrS = base + o;                o = align4w(o + (size_t)E);
    unsigned short* xb = (unsigned short*)(base + o); o = align4w(o + (size_t)N * XP / 2);
    float* xa   = (float*)(base + o);      o = align4w(o + (size_t)N * XP);
    unsigned short* h2b = (unsigned short*)(base + o);

    hipMemsetAsync(degi, 0, (size_t)N * sizeof(int), stream);

    deg_kernel<<<(E + 255) / 256, 256, 0, stream>>>(ei, degi, E);
    prep_kernel<<<1, 128, 0, stream>>>(b1, mean1, var1, gamma1, beta1,
                                       b2, mean2, var2, gamma2, beta2,
                                       A1f, B1f, A2f, B2f);
    scanA_kernel<<<NB, 256, 0, stream>>>(degi, x, offs, bsum, dinv, xb, N);
    scanB_kernel<<<1, 256, 0, stream>>>(bsum, NB);
    scanC_kernel<<<NB, 256, 0, stream>>>(offs, bsum, N);
    fill_kernel<<<(E + 255) / 256, 256, 0, stream>>>(ei, offs, csrS, E);

    gather_x_kernel<<<(N + 3) / 4, 256, 0, stream>>>(xb, dinv, offs, csrS, xa, N);
    gemm12_kernel<<<(N + 15) / 16, 256, 0, stream>>>(xa, W1, W2, A1f, B1f, A2f, dinv, h2b, N);
    gfinal_kernel<<<(N + 3) / 4, 256, 0, stream>>>(h2b, dinv, offs, csrS, B2f, Wfc, bfc, out, N);
}

// Round 6
// 190.608 us; speedup vs baseline: 1.0782x; 1.0782x over previous
//
#include <hip/hip_runtime.h>

#define EPS 1e-5f

constexpr int FIN = 22;   // input feature dim
constexpr int XP  = 32;   // padded x feature stride
constexpr int H   = 128;  // hidden dim
constexpr int SLICE_SHIFT = 17;  // 131072 CSR entries (512KB) per slice
constexpr int EPB = 2048;        // edges per scatter block-chunk

// bf16 helpers (bit-level, RN-even)
static __device__ __forceinline__ unsigned short f2bf(float f) {
    unsigned int u = __float_as_uint(f);
    unsigned int r = (u + 0x7fffu + ((u >> 16) & 1u)) >> 16;
    return (unsigned short)r;
}
static __device__ __forceinline__ float bflo(unsigned int u) {  // low bf16 of a dword
    return __uint_as_float(u << 16);
}
static __device__ __forceinline__ float bfhi(unsigned int u) {  // high bf16 of a dword
    return __uint_as_float(u & 0xffff0000u);
}

// ---------------- degree + in-edge rank (one atomic pass) ----------------
__global__ void rank_kernel(const int* __restrict__ ei, int* __restrict__ degi,
                            int* __restrict__ rank, int E) {
    int e = blockIdx.x * blockDim.x + threadIdx.x;
    if (e < E) rank[e] = atomicAdd(&degi[ei[E + e]], 1);
}

// ---------------- BN constant prep ----------------
__global__ void prep_kernel(const float* __restrict__ b1, const float* __restrict__ mean1,
                            const float* __restrict__ var1, const float* __restrict__ gamma1,
                            const float* __restrict__ beta1,
                            const float* __restrict__ b2, const float* __restrict__ mean2,
                            const float* __restrict__ var2, const float* __restrict__ gamma2,
                            const float* __restrict__ beta2,
                            float* __restrict__ A1f, float* __restrict__ B1f,
                            float* __restrict__ A2f, float* __restrict__ B2f) {
    int t = threadIdx.x;
    if (t < H) {
        float A1 = gamma1[t] * rsqrtf(var1[t] + EPS);
        A1f[t] = A1;
        B1f[t] = (b1[t] - mean1[t]) * A1 + beta1[t];
        float A2 = gamma2[t] * rsqrtf(var2[t] + EPS);
        A2f[t] = A2;
        B2f[t] = (b2[t] - mean2[t]) * A2 + beta2[t];
    }
}

// ---------------- scan phase A: per-block exclusive scan + dinv + xr = bf16(x*dinv) ----------------
__global__ __launch_bounds__(256) void scanA_kernel(
    const int* __restrict__ degi, const float* __restrict__ x,
    int* __restrict__ offs, int* __restrict__ bsum,
    float* __restrict__ dinv, unsigned short* __restrict__ xb, int N) {
    __shared__ int sh[256];
    const int t = threadIdx.x;
    const int i = blockIdx.x * 256 + t;
    int v = (i < N) ? degi[i] : 0;
    sh[t] = v;
    __syncthreads();
    int val = v;
    for (int off = 1; off < 256; off <<= 1) {
        int add = (t >= off) ? sh[t - off] : 0;
        __syncthreads();
        val += add;
        sh[t] = val;
        __syncthreads();
    }
    if (i < N) offs[i] = val - v;          // exclusive within block
    if (t == 255) bsum[blockIdx.x] = val;  // block total
    if (i < N) {
        float di = rsqrtf((float)v + 1.0f); // +1 self-loop
        dinv[i] = di;
#pragma unroll
        for (int k = 0; k < XP; ++k)
            xb[i * XP + k] = (k < FIN) ? f2bf(x[i * FIN + k] * di) : (unsigned short)0;
    }
}

// ---------------- scan phase B: exclusive scan of block sums ----------------
__global__ __launch_bounds__(256) void scanB_kernel(int* __restrict__ bsum, int nb) {
    __shared__ int sh[256];
    const int t = threadIdx.x;
    int v = (t < nb) ? bsum[t] : 0;
    sh[t] = v;
    __syncthreads();
    int val = v;
    for (int off = 1; off < 256; off <<= 1) {
        int add = (t >= off) ? sh[t - off] : 0;
        __syncthreads();
        val += add;
        sh[t] = val;
        __syncthreads();
    }
    if (t < nb) bsum[t] = val - v;
}

// ---------------- scan phase C: add block base; offs stays EXCLUSIVE ----------------
__global__ void scanC_kernel(int* __restrict__ offs, const int* __restrict__ bsum,
                             int N, int E) {
    int i = blockIdx.x * blockDim.x + threadIdx.x;
    if (i < N) offs[i] += bsum[blockIdx.x];
    if (blockIdx.x == 0 && threadIdx.x == 0) offs[N] = E;
}

// ---------------- XCD-sliced CSR scatter ----------------
// grid = ceil(E/EPB)*8; r = blockIdx&7 targets XCD r (round-robin heuristic).
// Block stores only positions in slice r -> each 512KB slice written by one XCD,
// lines accumulate all 16 slot-writes in that XCD's L2 before one writeback.
__global__ __launch_bounds__(256) void scatter8_kernel(
    const int* __restrict__ ei, const int* __restrict__ rank,
    const int* __restrict__ offs, int* __restrict__ csrS, int E, int nslice) {
    const int r = blockIdx.x & 7;
    if (r >= nslice) return;
    const int chunk = blockIdx.x >> 3;
    const int e1 = min(chunk * EPB + EPB, E);
    for (int e = chunk * EPB + threadIdx.x; e < e1; e += 256) {
        int d = ei[E + e];
        int p = offs[d] + rank[e];
        if ((p >> SLICE_SHIFT) == r) csrS[p] = ei[e];
    }
}
// CSR range of node d = [ offs[d], offs[d+1] )

// ---------------- layer-1 gather: unweighted sum of pre-scaled rows, *dinv at end ----------------
// wave = 8 groups x 8 lanes; 2-edge unrolled body for MLP
__global__ __launch_bounds__(256) void gather_x_kernel(
    const unsigned short* __restrict__ xb, const float* __restrict__ dinv,
    const int* __restrict__ offs, const int* __restrict__ csrS,
    float* __restrict__ xa, int N) {
    const int tid  = threadIdx.x;
    const int node = blockIdx.x * 4 + (tid >> 6);
    const int lane = tid & 63;
    if (node >= N) return;
    const int g  = lane >> 3;      // group 0..7
    const int fl = lane & 7;       // lane in group
    const int beg = offs[node];
    const int end = offs[node + 1];

    float acc0 = 0.f, acc1 = 0.f, acc2 = 0.f, acc3 = 0.f;
    if (g == 0) {  // self row, weight 1 (own dinv already folded in)
        ushort4 v = *reinterpret_cast<const ushort4*>(xb + (size_t)node * XP + fl * 4);
        acc0 = bflo(v.x); acc1 = bflo(v.y);
        acc2 = bflo(v.z); acc3 = bflo(v.w);
    }
    int e = beg + g;
    for (; e + 8 < end; e += 16) {
        int s0 = csrS[e];
        int s1 = csrS[e + 8];
        ushort4 v0 = *reinterpret_cast<const ushort4*>(xb + (size_t)s0 * XP + fl * 4);
        ushort4 v1 = *reinterpret_cast<const ushort4*>(xb + (size_t)s1 * XP + fl * 4);
        acc0 += bflo(v0.x) + bflo(v1.x);
        acc1 += bflo(v0.y) + bflo(v1.y);
        acc2 += bflo(v0.z) + bflo(v1.z);
        acc3 += bflo(v0.w) + bflo(v1.w);
    }
    if (e < end) {
        int s = csrS[e];
        ushort4 v = *reinterpret_cast<const ushort4*>(xb + (size_t)s * XP + fl * 4);
        acc0 += bflo(v.x); acc1 += bflo(v.y);
        acc2 += bflo(v.z); acc3 += bflo(v.w);
    }
#pragma unroll
    for (int off = 8; off < 64; off <<= 1) {
        acc0 += __shfl_xor(acc0, off);
        acc1 += __shfl_xor(acc1, off);
        acc2 += __shfl_xor(acc2, off);
        acc3 += __shfl_xor(acc3, off);
    }
    if (g == 0) {
        float di = dinv[node];
        float4 o = make_float4(acc0 * di, acc1 * di, acc2 * di, acc3 * di);
        *reinterpret_cast<float4*>(xa + (size_t)node * XP + fl * 4) = o;
    }
}

// ---------------- fused gemm1+BN1+ReLU+gemm2 (h1 stays in LDS); h2r = h2*A2*dinv ----------------
__global__ __launch_bounds__(256) void gemm12_kernel(
    const float* __restrict__ xa, const float* __restrict__ W1, const float* __restrict__ W2,
    const float* __restrict__ A1f, const float* __restrict__ B1f, const float* __restrict__ A2f,
    const float* __restrict__ dinv, unsigned short* __restrict__ h2b, int N) {
    __shared__ float lds1[16 * XP];        // xa tile
    __shared__ float lds2[H * 20];         // h1 tile, transposed [k][row], pad 20
    const int tid = threadIdx.x;
    const int m0  = blockIdx.x * 16;

    for (int idx = tid; idx < 16 * XP; idx += 256) {
        int row = m0 + (idx >> 5);
        lds1[idx] = (row < N) ? xa[(size_t)m0 * XP + idx] : 0.0f;
    }
    __syncthreads();

    const int f  = tid & 127;
    const int mg = tid >> 7;

    // gemm1
    float acc1[8];
#pragma unroll
    for (int j = 0; j < 8; ++j) acc1[j] = 0.0f;
    for (int k = 0; k < FIN; ++k) {
        float w = W1[k * H + f];
#pragma unroll
        for (int j = 0; j < 8; ++j) acc1[j] += lds1[(mg * 8 + j) * XP + k] * w;
    }
    const float A1 = A1f[f], B1 = B1f[f];
    float4 h1a, h1b;
    h1a.x = fmaxf(acc1[0] * A1 + B1, 0.f); h1a.y = fmaxf(acc1[1] * A1 + B1, 0.f);
    h1a.z = fmaxf(acc1[2] * A1 + B1, 0.f); h1a.w = fmaxf(acc1[3] * A1 + B1, 0.f);
    h1b.x = fmaxf(acc1[4] * A1 + B1, 0.f); h1b.y = fmaxf(acc1[5] * A1 + B1, 0.f);
    h1b.z = fmaxf(acc1[6] * A1 + B1, 0.f); h1b.w = fmaxf(acc1[7] * A1 + B1, 0.f);
    *reinterpret_cast<float4*>(&lds2[f * 20 + mg * 8])     = h1a;
    *reinterpret_cast<float4*>(&lds2[f * 20 + mg * 8 + 4]) = h1b;
    __syncthreads();

    // gemm2
    float acc2[8];
#pragma unroll
    for (int j = 0; j < 8; ++j) acc2[j] = 0.0f;
    for (int k = 0; k < H; ++k) {
        float w = W2[k * H + f];
        float4 ha = *reinterpret_cast<const float4*>(&lds2[k * 20 + mg * 8]);
        float4 hb = *reinterpret_cast<const float4*>(&lds2[k * 20 + mg * 8 + 4]);
        acc2[0] += ha.x * w; acc2[1] += ha.y * w; acc2[2] += ha.z * w; acc2[3] += ha.w * w;
        acc2[4] += hb.x * w; acc2[5] += hb.y * w; acc2[6] += hb.z * w; acc2[7] += hb.w * w;
    }
    const float A2 = A2f[f];
#pragma unroll
    for (int j = 0; j < 8; ++j) {
        int node = m0 + mg * 8 + j;
        if (node < N) {
            float sc = A2 * dinv[node];   // fold own dinv into stored row
            h2b[(size_t)node * H + f] = f2bf(acc2[j] * sc);
        }
    }
}

// ---------------- fused: layer-2 gather (pure row sum) + BN2 + ReLU + FC + sigmoid ----------------
// wave = 4 groups x 16 lanes; 2-edge unrolled body for MLP
__global__ __launch_bounds__(256) void gfinal_kernel(
    const unsigned short* __restrict__ h2b, const float* __restrict__ dinv,
    const int* __restrict__ offs, const int* __restrict__ csrS,
    const float* __restrict__ B2f, const float* __restrict__ Wfc,
    const float* __restrict__ bfc, float* __restrict__ out, int N) {
    const int tid  = threadIdx.x;
    const int node = blockIdx.x * 4 + (tid >> 6);
    const int lane = tid & 63;
    if (node >= N) return;
    const int g  = lane >> 4;      // group 0..3
    const int fl = lane & 15;      // lane in group
    const int f0 = fl * 8;
    const int beg = offs[node];
    const int end = offs[node + 1];

    float acc[8];
#pragma unroll
    for (int j = 0; j < 8; ++j) acc[j] = 0.0f;

    if (g == 0) {  // self row, weight 1
        uint4 v = *reinterpret_cast<const uint4*>(h2b + (size_t)node * H + f0);
        acc[0] = bflo(v.x); acc[1] = bfhi(v.x);
        acc[2] = bflo(v.y); acc[3] = bfhi(v.y);
        acc[4] = bflo(v.z); acc[5] = bfhi(v.z);
        acc[6] = bflo(v.w); acc[7] = bfhi(v.w);
    }
    int e = beg + g;
    for (; e + 4 < end; e += 8) {
        int s0 = csrS[e];
        int s1 = csrS[e + 4];
        uint4 v0 = *reinterpret_cast<const uint4*>(h2b + (size_t)s0 * H + f0);
        uint4 v1 = *reinterpret_cast<const uint4*>(h2b + (size_t)s1 * H + f0);
        acc[0] += bflo(v0.x) + bflo(v1.x); acc[1] += bfhi(v0.x) + bfhi(v1.x);
        acc[2] += bflo(v0.y) + bflo(v1.y); acc[3] += bfhi(v0.y) + bfhi(v1.y);
        acc[4] += bflo(v0.z) + bflo(v1.z); acc[5] += bfhi(v0.z) + bfhi(v1.z);
        acc[6] += bflo(v0.w) + bflo(v1.w); acc[7] += bfhi(v0.w) + bfhi(v1.w);
    }
    if (e < end) {
        int s = csrS[e];
        uint4 v = *reinterpret_cast<const uint4*>(h2b + (size_t)s * H + f0);
        acc[0] += bflo(v.x); acc[1] += bfhi(v.x);
        acc[2] += bflo(v.y); acc[3] += bfhi(v.y);
        acc[4] += bflo(v.z); acc[5] += bfhi(v.z);
        acc[6] += bflo(v.w); acc[7] += bfhi(v.w);
    }
#pragma unroll
    for (int j = 0; j < 8; ++j) {
        acc[j] += __shfl_xor(acc[j], 16);
        acc[j] += __shfl_xor(acc[j], 32);
    }
    const float di = dinv[node];
    float p = 0.0f;
#pragma unroll
    for (int j = 0; j < 8; ++j)
        p += fmaxf(acc[j] * di + B2f[f0 + j], 0.0f) * Wfc[f0 + j];
#pragma unroll
    for (int off = 1; off < 16; off <<= 1) p += __shfl_xor(p, off);
    if (lane == 0) out[node] = 1.0f / (1.0f + expf(-(p + bfc[0])));
}

static inline size_t align4w(size_t w) { return (w + 3) & ~(size_t)3; }  // 16B align (words)

extern "C" void kernel_launch(void* const* d_in, const int* in_sizes, int n_in,
                              void* d_out, int out_size, void* d_ws, size_t ws_size,
                              hipStream_t stream) {
    const float* x      = (const float*)d_in[0];
    const int*   ei     = (const int*)d_in[1];
    const float* W1     = (const float*)d_in[2];
    const float* b1     = (const float*)d_in[3];
    const float* gamma1 = (const float*)d_in[4];
    const float* beta1  = (const float*)d_in[5];
    const float* mean1  = (const float*)d_in[6];
    const float* var1   = (const float*)d_in[7];
    const float* W2     = (const float*)d_in[8];
    const float* b2     = (const float*)d_in[9];
    const float* gamma2 = (const float*)d_in[10];
    const float* beta2  = (const float*)d_in[11];
    const float* mean2  = (const float*)d_in[12];
    const float* var2   = (const float*)d_in[13];
    const float* Wfc    = (const float*)d_in[14];
    const float* bfc    = (const float*)d_in[15];
    float* out = (float*)d_out;

    const int N = in_sizes[0] / FIN;   // 50000
    const int E = in_sizes[1] / 2;     // 800000
    const int NB = (N + 255) / 256;
    const int nslice = (E + (1 << SLICE_SHIFT) - 1) >> SLICE_SHIFT;  // 7 for E=800000

    // workspace layout (4-byte words, 16B-aligned sections)
    int* base = (int*)d_ws;
    size_t o = 0;
    int*   degi = base + o;                o = align4w(o + N);
    float* dinv = (float*)(base + o);      o = align4w(o + N);
    int*   offs = base + o;                o = align4w(o + N + 1);
    int*   bsum = base + o;                o = align4w(o + 256);
    float* A1f  = (float*)(base + o);      o = align4w(o + H);
    float* B1f  = (float*)(base + o);      o = align4w(o + H);
    float* A2f  = (float*)(base + o);      o = align4w(o + H);
    float* B2f  = (float*)(base + o);      o = align4w(o + H);
    int*   rank = base + o;                o = align4w(o + (size_t)E);
    int*   csrS = base + o;                o = align4w(o + (size_t)E);
    unsigned short* xb = (unsigned short*)(base + o); o = align4w(o + (size_t)N * XP / 2);
    float* xa   = (float*)(base + o);      o = align4w(o + (size_t)N * XP);
    unsigned short* h2b = (unsigned short*)(base + o);

    hipMemsetAsync(degi, 0, (size_t)N * sizeof(int), stream);

    rank_kernel<<<(E + 255) / 256, 256, 0, stream>>>(ei, degi, rank, E);
    prep_kernel<<<1, 128, 0, stream>>>(b1, mean1, var1, gamma1, beta1,
                                       b2, mean2, var2, gamma2, beta2,
                                       A1f, B1f, A2f, B2f);
    scanA_kernel<<<NB, 256, 0, stream>>>(degi, x, offs, bsum, dinv, xb, N);
    scanB_kernel<<<1, 256, 0, stream>>>(bsum, NB);
    scanC_kernel<<<NB, 256, 0, stream>>>(offs, bsum, N, E);
    scatter8_kernel<<<((E + EPB - 1) / EPB) * 8, 256, 0, stream>>>(
        ei, rank, offs, csrS, E, nslice);

    gather_x_kernel<<<(N + 3) / 4, 256, 0, stream>>>(xb, dinv, offs, csrS, xa, N);
    gemm12_kernel<<<(N + 15) / 16, 256, 0, stream>>>(xa, W1, W2, A1f, B1f, A2f, dinv, h2b, N);
    gfinal_kernel<<<(N + 3) / 4, 256, 0, stream>>>(h2b, dinv, offs, csrS, B2f, Wfc, bfc, out, N);
}